// Round 5
// baseline (1748.484 us; speedup 1.0000x reference)
//
#include <hip/hip_runtime.h>
#include <hip/hip_bf16.h>

#define N_NODES 50000
#define E_EDGES 500000
#define NREL    3
#define DIN     128
#define DOUT    128
#define BM      64
#define KB      32
#define NB      782     // ceil(N_NODES / BM)
#define CAP     1024    // entries per (rel, dst-block) bin; E[fill]=640, +15 sigma

// ---------------------------------------------------------------------------
// Phase 1: bin edges by (rel, dst >> 6). Entry packs (src << 6) | (dst & 63)
// (src < 50000 < 2^16 -> fits in 22 bits). Consecutive atomic winners write
// consecutive addresses -> L2 write coalescing, ~10 MB HBM writes vs ~96 MB
// for per-node slots. Overflow (P ~ 1e-40) drops edges, non-corrupting.
// ---------------------------------------------------------------------------
__global__ __launch_bounds__(256) void k_fill_bins(const int* __restrict__ src0,
                                                   const int* __restrict__ dst0,
                                                   const int* __restrict__ src1,
                                                   const int* __restrict__ dst1,
                                                   const int* __restrict__ src2,
                                                   const int* __restrict__ dst2,
                                                   int* __restrict__ bincnt,
                                                   int* __restrict__ bins) {
    int e = blockIdx.x * 256 + threadIdx.x;
    if (e >= E_EDGES) return;
    {
        int d = dst0[e];
        int bin = 0 * NB + (d >> 6);
        int p = atomicAdd(&bincnt[bin], 1);
        if (p < CAP) bins[((size_t)bin << 10) + p] = (src0[e] << 6) | (d & 63);
    }
    {
        int d = dst1[e];
        int bin = 1 * NB + (d >> 6);
        int p = atomicAdd(&bincnt[bin], 1);
        if (p < CAP) bins[((size_t)bin << 10) + p] = (src1[e] << 6) | (d & 63);
    }
    {
        int d = dst2[e];
        int bin = 2 * NB + (d >> 6);
        int p = atomicAdd(&bincnt[bin], 1);
        if (p < CAP) bins[((size_t)bin << 10) + p] = (src2[e] << 6) | (d & 63);
    }
}

// ---------------------------------------------------------------------------
// Phase 2 (fused): per 64-node block, for each K-source (agg_r0..2, x) build
// the 64x128 A-tile in LDS, then accumulate GEMM vs matching W. Gather is
// EDGE-PARALLEL: each wave takes interleaved chunks of 8 bin entries; the
// whole wave covers one src row's 128 feats (feat lane and 64+lane -> ds_add
// banks lane%32, 2-way = free), accumulating via LDS float atomics. Per-node
// degree from a 64-int LDS histogram; normalize, then GEMM.
//   out = relu(concat(agg0,agg1,agg2,x) @ stack(W0,W1,W2,Wl) + b)
// ---------------------------------------------------------------------------
__global__ __launch_bounds__(256) void k_fused(const float* __restrict__ x,
                                               const int* __restrict__ bincnt,
                                               const int* __restrict__ bins,
                                               const float* __restrict__ W0,
                                               const float* __restrict__ W1,
                                               const float* __restrict__ W2,
                                               const float* __restrict__ Wl,
                                               const float* __restrict__ bias,
                                               float* __restrict__ out) {
    __shared__ float Ag[BM][132];    // 33.8 KB
    __shared__ float Bs[KB][DOUT];   // 16.4 KB
    __shared__ int   degS[BM];

    const int tid   = threadIdx.x;
    const int mbase = blockIdx.x * BM;
    const int wave  = tid >> 6;      // 0..3
    const int lane  = tid & 63;
    const int rg    = tid >> 5;      // 0..7 -> output rows rg*8..rg*8+7
    const int cg    = tid & 31;      // output cols cg*4..cg*4+3

    float acc[8][4];
#pragma unroll
    for (int i = 0; i < 8; ++i)
#pragma unroll
        for (int j = 0; j < 4; ++j) acc[i][j] = 0.f;

    for (int rel = 0; rel < 4; ++rel) {
        __syncthreads();   // previous rel's Ag reads complete before overwrite

        if (rel < 3) {
            // zero Ag + degS
            float* az = &Ag[0][0];
            for (int i = tid * 4; i < BM * 132; i += 1024)
                *reinterpret_cast<float4*>(az + i) = make_float4(0.f, 0.f, 0.f, 0.f);
            if (tid < BM) degS[tid] = 0;
            __syncthreads();

            const int bin  = rel * NB + blockIdx.x;
            const int cnt_ = min(bincnt[bin], CAP);
            const int* bp  = bins + ((size_t)bin << 10);

            int i = wave * 8;
            for (; i + 8 <= cnt_; i += 32) {
                int4 ea = *reinterpret_cast<const int4*>(bp + i);
                int4 eb = *reinterpret_cast<const int4*>(bp + i + 4);
                int ee[8] = {ea.x, ea.y, ea.z, ea.w, eb.x, eb.y, eb.z, eb.w};
                float va[8], vb[8];
#pragma unroll
                for (int k = 0; k < 8; ++k) {
                    const float* xp = x + (size_t)(ee[k] >> 6) * DIN + lane;
                    va[k] = xp[0];
                    vb[k] = xp[64];
                }
#pragma unroll
                for (int k = 0; k < 8; ++k) {
                    int lo = ee[k] & 63;
                    atomicAdd(&Ag[lo][lane], va[k]);
                    atomicAdd(&Ag[lo][64 + lane], vb[k]);
                }
                if (lane == 0) {
#pragma unroll
                    for (int k = 0; k < 8; ++k) atomicAdd(&degS[ee[k] & 63], 1);
                }
            }
            // per-wave tail (< 8 entries)
            int iend = i + 8 < cnt_ ? i + 8 : cnt_;
            for (int k2 = i; k2 < iend; ++k2) {
                int e  = bp[k2];
                int lo = e & 63;
                const float* xp = x + (size_t)(e >> 6) * DIN + lane;
                atomicAdd(&Ag[lo][lane], xp[0]);
                atomicAdd(&Ag[lo][64 + lane], xp[64]);
                if (lane == 0) atomicAdd(&degS[lo], 1);
            }
            __syncthreads();

            // normalize: thread -> row tid>>2, col chunk (tid&3)*32
            {
                int row = tid >> 2;
                int c0  = (tid & 3) * 32;
                float inv = 1.0f / (float)max(degS[row], 1);
#pragma unroll
                for (int j = 0; j < 8; ++j) {
                    float4* p4 = reinterpret_cast<float4*>(&Ag[row][c0 + j * 4]);
                    float4 v = *p4;
                    v.x *= inv; v.y *= inv; v.z *= inv; v.w *= inv;
                    *p4 = v;
                }
            }
            // Ag writes ordered before FMA reads by the barrier after B-staging
        } else {
            // direct copy of x rows: 64 rows x 32 float4
#pragma unroll
            for (int j = 0; j < 8; ++j) {
                int idx = tid + j * 256;         // 0..2047
                int row = idx >> 5;              // 0..63
                int q   = idx & 31;              // float4 index within row
                int node = mbase + row;
                float4 v = make_float4(0.f, 0.f, 0.f, 0.f);
                if (node < N_NODES)
                    v = *reinterpret_cast<const float4*>(x + (size_t)node * DIN + q * 4);
                *reinterpret_cast<float4*>(&Ag[row][q * 4]) = v;
            }
        }

        const float* W = (rel == 0) ? W0 : (rel == 1) ? W1 : (rel == 2) ? W2 : Wl;

        for (int kc = 0; kc < 4; ++kc) {         // 128 K in chunks of 32
            // stage B chunk: 32 x 128 floats
#pragma unroll
            for (int j = 0; j < 4; ++j) {
                int idx = tid + j * 256;         // 0..1023
                int kk  = idx >> 5;              // 0..31
                int cq  = idx & 31;
                float4 v = *reinterpret_cast<const float4*>(W + (size_t)(kc * KB + kk) * DOUT + cq * 4);
                *reinterpret_cast<float4*>(&Bs[kk][cq * 4]) = v;
            }
            __syncthreads();

#pragma unroll
            for (int k = 0; k < KB; ++k) {
                float a[8], bb[4];
#pragma unroll
                for (int i = 0; i < 8; ++i) a[i] = Ag[rg * 8 + i][kc * KB + k];
                *reinterpret_cast<float4*>(&bb[0]) = *reinterpret_cast<const float4*>(&Bs[k][cg * 4]);
#pragma unroll
                for (int i = 0; i < 8; ++i)
#pragma unroll
                    for (int j = 0; j < 4; ++j) acc[i][j] += a[i] * bb[j];
            }
            __syncthreads();
        }
    }

    // epilogue: bias + relu
    float4 bv = *reinterpret_cast<const float4*>(bias + cg * 4);
#pragma unroll
    for (int i = 0; i < 8; ++i) {
        int node = mbase + rg * 8 + i;
        if (node < N_NODES) {
            float4 o;
            o.x = fmaxf(acc[i][0] + bv.x, 0.f);
            o.y = fmaxf(acc[i][1] + bv.y, 0.f);
            o.z = fmaxf(acc[i][2] + bv.z, 0.f);
            o.w = fmaxf(acc[i][3] + bv.w, 0.f);
            *reinterpret_cast<float4*>(out + (size_t)node * DOUT + cg * 4) = o;
        }
    }
}

// ---------------------------------------------------------------------------
extern "C" void kernel_launch(void* const* d_in, const int* in_sizes, int n_in,
                              void* d_out, int out_size, void* d_ws, size_t ws_size,
                              hipStream_t stream) {
    const float* x    = (const float*)d_in[0];
    const int* src0   = (const int*)d_in[1];
    const int* dst0   = (const int*)d_in[2];
    const int* src1   = (const int*)d_in[3];
    const int* dst1   = (const int*)d_in[4];
    const int* src2   = (const int*)d_in[5];
    const int* dst2   = (const int*)d_in[6];
    const float* W0   = (const float*)d_in[7];
    const float* W1   = (const float*)d_in[8];
    const float* W2   = (const float*)d_in[9];
    const float* Wl   = (const float*)d_in[10];
    const float* bias = (const float*)d_in[11];
    float* out        = (float*)d_out;

    // workspace: bincnt (padded to 16 KB) + bins (3*782*1024*4 = 9.6 MB)
    char* p = (char*)d_ws;
    int* bincnt = (int*)p;  p += 16384;           // NREL*NB*4 = 9384 B, padded
    int* bins   = (int*)p;

    hipMemsetAsync(bincnt, 0, (size_t)NREL * NB * sizeof(int), stream);

    const int eb = (E_EDGES + 255) / 256;
    k_fill_bins<<<eb, 256, 0, stream>>>(src0, dst0, src1, dst1, src2, dst2, bincnt, bins);

    k_fused<<<NB, 256, 0, stream>>>(x, bincnt, bins, W0, W1, W2, Wl, bias, out);
}

// Round 6
// 435.018 us; speedup vs baseline: 4.0193x; 4.0193x over previous
//
#include <hip/hip_runtime.h>
#include <hip/hip_bf16.h>

#define N_NODES 50000
#define E_EDGES 500000
#define NREL    3
#define DIN     128
#define DOUT    128
#define SLOT    40   // max in-degree per (rel,node); Poisson(10) tail P(exceed) ~ 1e-8 total
#define CPAD    16   // counter padding: one counter per 64B line (atomic ping-pong probe)

// ---------------------------------------------------------------------------
// Phase 1: bin edges into per-(rel,node) fixed slots. cur[seg*CPAD] ends as
// in-degree; slots[seg*SLOT + 0..deg) hold u16 srcs. Overflow drops edges
// (non-corrupting, P~1e-8).
// ---------------------------------------------------------------------------
__global__ __launch_bounds__(256) void k_fill_direct(const int* __restrict__ src0,
                                                     const int* __restrict__ dst0,
                                                     const int* __restrict__ src1,
                                                     const int* __restrict__ dst1,
                                                     const int* __restrict__ src2,
                                                     const int* __restrict__ dst2,
                                                     int* __restrict__ cur,
                                                     unsigned short* __restrict__ slots) {
    int e = blockIdx.x * 256 + threadIdx.x;
    if (e >= E_EDGES) return;

    int d0 = dst0[e];
    int p0 = atomicAdd(&cur[(size_t)(0 * N_NODES + d0) * CPAD], 1);
    if (p0 < SLOT) slots[(size_t)(0 * N_NODES + d0) * SLOT + p0] = (unsigned short)src0[e];

    int d1 = dst1[e];
    int p1 = atomicAdd(&cur[(size_t)(1 * N_NODES + d1) * CPAD], 1);
    if (p1 < SLOT) slots[(size_t)(1 * N_NODES + d1) * SLOT + p1] = (unsigned short)src1[e];

    int d2 = dst2[e];
    int p2 = atomicAdd(&cur[(size_t)(2 * N_NODES + d2) * CPAD], 1);
    if (p2 < SLOT) slots[(size_t)(2 * N_NODES + d2) * SLOT + p2] = (unsigned short)src2[e];
}

// ---------------------------------------------------------------------------
// Phase 2 (fused): per 64-node block, for each of the 4 K-sources
// (agg_r0, agg_r1, agg_r2, x) build the 64x128 A-tile in LDS, then accumulate
// the GEMM against the matching W. Epilogue: +bias, ReLU.
//   out = relu(concat(agg0,agg1,agg2,x) @ stack(W0,W1,W2,Wl) + b)
//
// Gather: wave = four 16-lane groups, each owns 4 rows serially; edge loop
// unrolled x4 via one ushort4 slot prefetch -> 8 outstanding float4 x-loads
// per group (32/wave). A-tile row-major Ag[64][132].
// KB=8 B-staging keeps LDS at 37.9 KB -> 4 blocks/CU (vs 3 at KB=32).
// ---------------------------------------------------------------------------
#define BM 64
#define KB 8

__global__ __launch_bounds__(256) void k_fused(const float* __restrict__ x,
                                               const int* __restrict__ cur,
                                               const unsigned short* __restrict__ slots,
                                               const float* __restrict__ W0,
                                               const float* __restrict__ W1,
                                               const float* __restrict__ W2,
                                               const float* __restrict__ Wl,
                                               const float* __restrict__ bias,
                                               float* __restrict__ out) {
    __shared__ float Ag[BM][132];    // 33.8 KB
    __shared__ float Bs[KB][DOUT];   // 4.1 KB

    const int tid   = threadIdx.x;
    const int mbase = blockIdx.x * BM;
    const int wave  = tid >> 6;      // 0..3
    const int lane  = tid & 63;
    const int g     = lane >> 4;     // 16-lane group 0..3
    const int li    = lane & 15;     // lane within group; covers feats li*8..li*8+7
    const int rg    = tid >> 5;      // 0..7 -> output rows rg*8..rg*8+7
    const int cg    = tid & 31;      // output cols cg*4..cg*4+3

    float acc[8][4];
#pragma unroll
    for (int i = 0; i < 8; ++i)
#pragma unroll
        for (int j = 0; j < 4; ++j) acc[i][j] = 0.f;

    for (int rel = 0; rel < 4; ++rel) {
        __syncthreads();   // previous rel's Ag reads complete before overwrite

        if (rel < 3) {
            // four rows in flight per wave: row = wave*16 + g*4 + t
#pragma unroll
            for (int t = 0; t < 4; ++t) {
                const int local = wave * 16 + g * 4 + t;
                const int node  = mbase + local;
                float aA0 = 0.f, aA1 = 0.f, aA2 = 0.f, aA3 = 0.f;
                float aB0 = 0.f, aB1 = 0.f, aB2 = 0.f, aB3 = 0.f;
                int dd = 0;
                if (node < N_NODES) {
                    const int seg = rel * N_NODES + node;
                    int d = cur[(size_t)seg * CPAD];
                    d = min(d, SLOT);
                    dd = d;
                    const unsigned short* sb = slots + (size_t)seg * SLOT;
                    const float* xb = x + (size_t)li * 8;
                    int i = 0;
                    for (; i + 4 <= d; i += 4) {
                        ushort4 s4 = *reinterpret_cast<const ushort4*>(sb + i);
                        const float* q0 = xb + (size_t)s4.x * DIN;
                        const float* q1 = xb + (size_t)s4.y * DIN;
                        const float* q2 = xb + (size_t)s4.z * DIN;
                        const float* q3 = xb + (size_t)s4.w * DIN;
                        float4 u0 = *reinterpret_cast<const float4*>(q0);
                        float4 w0 = *reinterpret_cast<const float4*>(q0 + 4);
                        float4 u1 = *reinterpret_cast<const float4*>(q1);
                        float4 w1 = *reinterpret_cast<const float4*>(q1 + 4);
                        float4 u2 = *reinterpret_cast<const float4*>(q2);
                        float4 w2 = *reinterpret_cast<const float4*>(q2 + 4);
                        float4 u3 = *reinterpret_cast<const float4*>(q3);
                        float4 w3 = *reinterpret_cast<const float4*>(q3 + 4);
                        aA0 += (u0.x + u1.x) + (u2.x + u3.x);
                        aA1 += (u0.y + u1.y) + (u2.y + u3.y);
                        aA2 += (u0.z + u1.z) + (u2.z + u3.z);
                        aA3 += (u0.w + u1.w) + (u2.w + u3.w);
                        aB0 += (w0.x + w1.x) + (w2.x + w3.x);
                        aB1 += (w0.y + w1.y) + (w2.y + w3.y);
                        aB2 += (w0.z + w1.z) + (w2.z + w3.z);
                        aB3 += (w0.w + w1.w) + (w2.w + w3.w);
                    }
                    for (; i < d; ++i) {
                        int s0 = sb[i];
                        const float* q0 = xb + (size_t)s0 * DIN;
                        float4 u0 = *reinterpret_cast<const float4*>(q0);
                        float4 w0 = *reinterpret_cast<const float4*>(q0 + 4);
                        aA0 += u0.x; aA1 += u0.y; aA2 += u0.z; aA3 += u0.w;
                        aB0 += w0.x; aB1 += w0.y; aB2 += w0.z; aB3 += w0.w;
                    }
                }
                const float sc = 1.0f / (float)max(dd, 1);
                float4 wA = make_float4(aA0 * sc, aA1 * sc, aA2 * sc, aA3 * sc);
                float4 wB = make_float4(aB0 * sc, aB1 * sc, aB2 * sc, aB3 * sc);
                *reinterpret_cast<float4*>(&Ag[local][li * 8])     = wA;
                *reinterpret_cast<float4*>(&Ag[local][li * 8 + 4]) = wB;
            }
        } else {
            // direct copy of x rows: 64 rows x 32 float4
#pragma unroll
            for (int j = 0; j < 8; ++j) {
                int idx = tid + j * 256;         // 0..2047
                int row = idx >> 5;              // 0..63
                int q   = idx & 31;              // float4 index within row
                int node = mbase + row;
                float4 v = make_float4(0.f, 0.f, 0.f, 0.f);
                if (node < N_NODES)
                    v = *reinterpret_cast<const float4*>(x + (size_t)node * DIN + q * 4);
                *reinterpret_cast<float4*>(&Ag[row][q * 4]) = v;
            }
        }
        __syncthreads();

        const float* W = (rel == 0) ? W0 : (rel == 1) ? W1 : (rel == 2) ? W2 : Wl;

        for (int kc = 0; kc < 16; ++kc) {        // 128 K in chunks of 8
            // stage B chunk: 8 x 128 floats = 256 float4, one per thread
            {
                int kk = tid >> 5;               // 0..7
                int cq = tid & 31;
                float4 v = *reinterpret_cast<const float4*>(W + (size_t)(kc * KB + kk) * DOUT + cq * 4);
                *reinterpret_cast<float4*>(&Bs[kk][cq * 4]) = v;
            }
            __syncthreads();

#pragma unroll
            for (int k = 0; k < KB; ++k) {
                float a[8], bb[4];
#pragma unroll
                for (int i = 0; i < 8; ++i) a[i] = Ag[rg * 8 + i][kc * KB + k];
                *reinterpret_cast<float4*>(&bb[0]) = *reinterpret_cast<const float4*>(&Bs[k][cg * 4]);
#pragma unroll
                for (int i = 0; i < 8; ++i)
#pragma unroll
                    for (int j = 0; j < 4; ++j) acc[i][j] += a[i] * bb[j];
            }
            __syncthreads();
        }
    }

    // epilogue: bias + relu
    float4 bv = *reinterpret_cast<const float4*>(bias + cg * 4);
#pragma unroll
    for (int i = 0; i < 8; ++i) {
        int node = mbase + rg * 8 + i;
        if (node < N_NODES) {
            float4 o;
            o.x = fmaxf(acc[i][0] + bv.x, 0.f);
            o.y = fmaxf(acc[i][1] + bv.y, 0.f);
            o.z = fmaxf(acc[i][2] + bv.z, 0.f);
            o.w = fmaxf(acc[i][3] + bv.w, 0.f);
            *reinterpret_cast<float4*>(out + (size_t)node * DOUT + cg * 4) = o;
        }
    }
}

// ---------------------------------------------------------------------------
extern "C" void kernel_launch(void* const* d_in, const int* in_sizes, int n_in,
                              void* d_out, int out_size, void* d_ws, size_t ws_size,
                              hipStream_t stream) {
    const float* x    = (const float*)d_in[0];
    const int* src0   = (const int*)d_in[1];
    const int* dst0   = (const int*)d_in[2];
    const int* src1   = (const int*)d_in[3];
    const int* dst1   = (const int*)d_in[4];
    const int* src2   = (const int*)d_in[5];
    const int* dst2   = (const int*)d_in[6];
    const float* W0   = (const float*)d_in[7];
    const float* W1   = (const float*)d_in[8];
    const float* W2   = (const float*)d_in[9];
    const float* Wl   = (const float*)d_in[10];
    const float* bias = (const float*)d_in[11];
    float* out        = (float*)d_out;

    // workspace: cur (150K * CPAD * 4 = 9.6 MB) + slots (150K * SLOT * 2 = 12 MB)
    char* p = (char*)d_ws;
    int* cur = (int*)p;  p += (size_t)NREL * N_NODES * CPAD * sizeof(int);
    unsigned short* slots = (unsigned short*)p;

    hipMemsetAsync(cur, 0, (size_t)NREL * N_NODES * CPAD * sizeof(int), stream);

    const int eb = (E_EDGES + 255) / 256;
    k_fill_direct<<<eb, 256, 0, stream>>>(src0, dst0, src1, dst1, src2, dst2, cur, slots);

    k_fused<<<(N_NODES + BM - 1) / BM, 256, 0, stream>>>(x, cur, slots,
                                                         W0, W1, W2, Wl, bias, out);
}

// Round 9
// 378.509 us; speedup vs baseline: 4.6194x; 1.1493x over previous
//
#include <hip/hip_runtime.h>
#include <hip/hip_bf16.h>

#define N_NODES 50000
#define E_EDGES 500000
#define NREL    3
#define DIN     128
#define DOUT    128
#define SLOT    40    // max in-degree per (rel,node); Poisson(10) tail P(exceed) ~ 1e-8 total
#define NB      782   // ceil(N_NODES / 64)
#define BM      64
#define KB      8

// ---- bf16 helpers (RNE pack, shift unpack) --------------------------------
__device__ __forceinline__ unsigned int f2bf(float f) {
    unsigned int u = __float_as_uint(f);
    unsigned int r = (u + 0x7FFFu + ((u >> 16) & 1u)) >> 16;
    return r;
}
__device__ __forceinline__ float bf2f_lo(unsigned int u) {   // low 16 bits
    return __uint_as_float(u << 16);
}
__device__ __forceinline__ float bf2f_hi(unsigned int u) {   // high 16 bits
    return __uint_as_float(u & 0xFFFF0000u);
}

// ---------------------------------------------------------------------------
// Phase 1: bin edges into per-(rel,node) fixed slots. cur[seg] ends as
// in-degree; slots[seg*SLOT + 0..deg) hold u16 srcs. Overflow drops edges
// (non-corrupting, P~1e-8).
// ---------------------------------------------------------------------------
__global__ __launch_bounds__(256) void k_fill_direct(const int* __restrict__ src0,
                                                     const int* __restrict__ dst0,
                                                     const int* __restrict__ src1,
                                                     const int* __restrict__ dst1,
                                                     const int* __restrict__ src2,
                                                     const int* __restrict__ dst2,
                                                     int* __restrict__ cur,
                                                     unsigned short* __restrict__ slots) {
    int e = blockIdx.x * 256 + threadIdx.x;
    if (e >= E_EDGES) return;

    int d0 = dst0[e];
    int p0 = atomicAdd(&cur[0 * N_NODES + d0], 1);
    if (p0 < SLOT) slots[(size_t)(0 * N_NODES + d0) * SLOT + p0] = (unsigned short)src0[e];

    int d1 = dst1[e];
    int p1 = atomicAdd(&cur[1 * N_NODES + d1], 1);
    if (p1 < SLOT) slots[(size_t)(1 * N_NODES + d1) * SLOT + p1] = (unsigned short)src1[e];

    int d2 = dst2[e];
    int p2 = atomicAdd(&cur[2 * N_NODES + d2], 1);
    if (p2 < SLOT) slots[(size_t)(2 * N_NODES + d2) * SLOT + p2] = (unsigned short)src2[e];
}

// ---------------------------------------------------------------------------
// Phase 2: cast x to bf16 (halves gather traffic). 8 floats / thread.
// ---------------------------------------------------------------------------
__global__ __launch_bounds__(256) void k_xcast(const float* __restrict__ x,
                                               unsigned short* __restrict__ xb) {
    int i = (blockIdx.x * 256 + threadIdx.x) * 8;
    if (i >= N_NODES * DIN) return;
    float4 a = *reinterpret_cast<const float4*>(x + i);
    float4 b = *reinterpret_cast<const float4*>(x + i + 4);
    uint4 o;
    o.x = f2bf(a.x) | (f2bf(a.y) << 16);
    o.y = f2bf(a.z) | (f2bf(a.w) << 16);
    o.z = f2bf(b.x) | (f2bf(b.y) << 16);
    o.w = f2bf(b.z) | (f2bf(b.w) << 16);
    *reinterpret_cast<uint4*>(xb + i) = o;
}

// ---------------------------------------------------------------------------
// Phase 3: gather-aggregate, one block per (rel, 64-node block). No LDS ->
// high occupancy; 2346 blocks -> ~9 blocks/CU. Wave = four 16-lane groups;
// each group serially owns 4 rows; edge loop unrolled x4 (4 outstanding 16B
// bf16-row loads per lane). Accumulate fp32, normalize by true degree,
// store bf16 row (16 lanes x 16B = 256B coalesced).
// ---------------------------------------------------------------------------
__global__ __launch_bounds__(256) void k_gather(const unsigned short* __restrict__ xb,
                                                const int* __restrict__ cur,
                                                const unsigned short* __restrict__ slots,
                                                unsigned short* __restrict__ aggb) {
    const int rel  = blockIdx.x / NB;
    const int blk  = blockIdx.x % NB;
    const int mbase = blk * BM;
    const int tid  = threadIdx.x;
    const int wave = tid >> 6;
    const int lane = tid & 63;
    const int g    = lane >> 4;
    const int li   = lane & 15;      // covers feats li*8 .. li*8+7

#pragma unroll
    for (int t = 0; t < 4; ++t) {
        const int local = wave * 16 + g * 4 + t;
        const int node  = mbase + local;
        if (node >= N_NODES) continue;
        const int seg = rel * N_NODES + node;
        const int dtrue = cur[seg];
        const int d = min(dtrue, SLOT);
        const unsigned short* sb = slots + (size_t)seg * SLOT;
        const unsigned short* xbb = xb + (size_t)li * 8;

        float acc[8];
#pragma unroll
        for (int k = 0; k < 8; ++k) acc[k] = 0.f;

        int i = 0;
        for (; i + 4 <= d; i += 4) {
            ushort4 s4 = *reinterpret_cast<const ushort4*>(sb + i);
            uint4 u0 = *reinterpret_cast<const uint4*>(xbb + (size_t)s4.x * DIN);
            uint4 u1 = *reinterpret_cast<const uint4*>(xbb + (size_t)s4.y * DIN);
            uint4 u2 = *reinterpret_cast<const uint4*>(xbb + (size_t)s4.z * DIN);
            uint4 u3 = *reinterpret_cast<const uint4*>(xbb + (size_t)s4.w * DIN);
            acc[0] += bf2f_lo(u0.x) + bf2f_lo(u1.x) + bf2f_lo(u2.x) + bf2f_lo(u3.x);
            acc[1] += bf2f_hi(u0.x) + bf2f_hi(u1.x) + bf2f_hi(u2.x) + bf2f_hi(u3.x);
            acc[2] += bf2f_lo(u0.y) + bf2f_lo(u1.y) + bf2f_lo(u2.y) + bf2f_lo(u3.y);
            acc[3] += bf2f_hi(u0.y) + bf2f_hi(u1.y) + bf2f_hi(u2.y) + bf2f_hi(u3.y);
            acc[4] += bf2f_lo(u0.z) + bf2f_lo(u1.z) + bf2f_lo(u2.z) + bf2f_lo(u3.z);
            acc[5] += bf2f_hi(u0.z) + bf2f_hi(u1.z) + bf2f_hi(u2.z) + bf2f_hi(u3.z);
            acc[6] += bf2f_lo(u0.w) + bf2f_lo(u1.w) + bf2f_lo(u2.w) + bf2f_lo(u3.w);
            acc[7] += bf2f_hi(u0.w) + bf2f_hi(u1.w) + bf2f_hi(u2.w) + bf2f_hi(u3.w);
        }
        for (; i < d; ++i) {
            uint4 u0 = *reinterpret_cast<const uint4*>(xbb + (size_t)sb[i] * DIN);
            acc[0] += bf2f_lo(u0.x); acc[1] += bf2f_hi(u0.x);
            acc[2] += bf2f_lo(u0.y); acc[3] += bf2f_hi(u0.y);
            acc[4] += bf2f_lo(u0.z); acc[5] += bf2f_hi(u0.z);
            acc[6] += bf2f_lo(u0.w); acc[7] += bf2f_hi(u0.w);
        }

        const float inv = 1.0f / (float)max(dtrue, 1);
        uint4 o;
        o.x = f2bf(acc[0] * inv) | (f2bf(acc[1] * inv) << 16);
        o.y = f2bf(acc[2] * inv) | (f2bf(acc[3] * inv) << 16);
        o.z = f2bf(acc[4] * inv) | (f2bf(acc[5] * inv) << 16);
        o.w = f2bf(acc[6] * inv) | (f2bf(acc[7] * inv) << 16);
        *reinterpret_cast<uint4*>(aggb + (size_t)seg * DIN + li * 8) = o;
    }
}

// ---------------------------------------------------------------------------
// Phase 4: GEMM  out = relu(concat(agg0,agg1,agg2)_bf16 ++ x_fp32 @ stack(W) + b).
// Agg tiles staged bf16 -> fp32 LDS; self-loop x tile staged directly from
// fp32 x (exact self-loop term, ~2us extra L3 traffic); W fp32; fp32 FMA.
// ---------------------------------------------------------------------------
__global__ __launch_bounds__(256) void k_gemm(const float* __restrict__ x,
                                              const unsigned short* __restrict__ aggb,
                                              const float* __restrict__ W0,
                                              const float* __restrict__ W1,
                                              const float* __restrict__ W2,
                                              const float* __restrict__ Wl,
                                              const float* __restrict__ bias,
                                              float* __restrict__ out) {
    __shared__ float Ag[BM][132];    // 33.8 KB
    __shared__ float Bs[KB][DOUT];   // 4.1 KB

    const int tid   = threadIdx.x;
    const int mbase = blockIdx.x * BM;
    const int rg    = tid >> 5;
    const int cg    = tid & 31;

    float acc[8][4];
#pragma unroll
    for (int i = 0; i < 8; ++i)
#pragma unroll
        for (int j = 0; j < 4; ++j) acc[i][j] = 0.f;

    for (int rel = 0; rel < 4; ++rel) {
        __syncthreads();

        if (rel < 3) {
            // stage A tile: 64 rows x 128 bf16 -> fp32 LDS. 1024 uint4, 4/thread.
            const unsigned short* Asrc = aggb + (size_t)rel * N_NODES * DIN;
#pragma unroll
            for (int j = 0; j < 4; ++j) {
                int idx = tid + j * 256;        // 0..1023
                int row = idx >> 4;             // 0..63
                int oct = idx & 15;             // 8-feat group
                int node = mbase + row;
                int nc = node < N_NODES ? node : N_NODES - 1;
                uint4 u = *reinterpret_cast<const uint4*>(Asrc + (size_t)nc * DIN + oct * 8);
                float4 f0 = make_float4(bf2f_lo(u.x), bf2f_hi(u.x), bf2f_lo(u.y), bf2f_hi(u.y));
                float4 f1 = make_float4(bf2f_lo(u.z), bf2f_hi(u.z), bf2f_lo(u.w), bf2f_hi(u.w));
                *reinterpret_cast<float4*>(&Ag[row][oct * 8])     = f0;
                *reinterpret_cast<float4*>(&Ag[row][oct * 8 + 4]) = f1;
            }
        } else {
            // self-loop tile from fp32 x: 64 rows x 32 float4, 8/thread
#pragma unroll
            for (int j = 0; j < 8; ++j) {
                int idx = tid + j * 256;        // 0..2047
                int row = idx >> 5;             // 0..63
                int q   = idx & 31;
                int node = mbase + row;
                float4 v = make_float4(0.f, 0.f, 0.f, 0.f);
                if (node < N_NODES)
                    v = *reinterpret_cast<const float4*>(x + (size_t)node * DIN + q * 4);
                *reinterpret_cast<float4*>(&Ag[row][q * 4]) = v;
            }
        }
        __syncthreads();

        const float* W = (rel == 0) ? W0 : (rel == 1) ? W1 : (rel == 2) ? W2 : Wl;

        for (int kc = 0; kc < 16; ++kc) {    // 128 K in chunks of 8
            {
                int kk = tid >> 5;           // 0..7
                int cq = tid & 31;
                float4 v = *reinterpret_cast<const float4*>(W + (size_t)(kc * KB + kk) * DOUT + cq * 4);
                *reinterpret_cast<float4*>(&Bs[kk][cq * 4]) = v;
            }
            __syncthreads();

#pragma unroll
            for (int k = 0; k < KB; ++k) {
                float a[8], bb[4];
#pragma unroll
                for (int i = 0; i < 8; ++i) a[i] = Ag[rg * 8 + i][kc * KB + k];
                *reinterpret_cast<float4*>(&bb[0]) = *reinterpret_cast<const float4*>(&Bs[k][cg * 4]);
#pragma unroll
                for (int i = 0; i < 8; ++i)
#pragma unroll
                    for (int j = 0; j < 4; ++j) acc[i][j] += a[i] * bb[j];
            }
            __syncthreads();
        }
    }

    float4 bv = *reinterpret_cast<const float4*>(bias + cg * 4);
#pragma unroll
    for (int i = 0; i < 8; ++i) {
        int node = mbase + rg * 8 + i;
        if (node < N_NODES) {
            float4 o;
            o.x = fmaxf(acc[i][0] + bv.x, 0.f);
            o.y = fmaxf(acc[i][1] + bv.y, 0.f);
            o.z = fmaxf(acc[i][2] + bv.z, 0.f);
            o.w = fmaxf(acc[i][3] + bv.w, 0.f);
            *reinterpret_cast<float4*>(out + (size_t)node * DOUT + cg * 4) = o;
        }
    }
}

// ---------------------------------------------------------------------------
// Fallback fused kernel (round-6 structure): used if ws too small.
// ---------------------------------------------------------------------------
__global__ __launch_bounds__(256) void k_fused_fb(const float* __restrict__ x,
                                                  const int* __restrict__ cur,
                                                  const unsigned short* __restrict__ slots,
                                                  const float* __restrict__ W0,
                                                  const float* __restrict__ W1,
                                                  const float* __restrict__ W2,
                                                  const float* __restrict__ Wl,
                                                  const float* __restrict__ bias,
                                                  float* __restrict__ out) {
    __shared__ float Ag[BM][132];
    __shared__ float Bs[KB][DOUT];

    const int tid   = threadIdx.x;
    const int mbase = blockIdx.x * BM;
    const int wave  = tid >> 6;
    const int lane  = tid & 63;
    const int g     = lane >> 4;
    const int li    = lane & 15;
    const int rg    = tid >> 5;
    const int cg    = tid & 31;

    float acc[8][4];
#pragma unroll
    for (int i = 0; i < 8; ++i)
#pragma unroll
        for (int j = 0; j < 4; ++j) acc[i][j] = 0.f;

    for (int rel = 0; rel < 4; ++rel) {
        __syncthreads();
        if (rel < 3) {
#pragma unroll
            for (int t = 0; t < 4; ++t) {
                const int local = wave * 16 + g * 4 + t;
                const int node  = mbase + local;
                float aA0 = 0.f, aA1 = 0.f, aA2 = 0.f, aA3 = 0.f;
                float aB0 = 0.f, aB1 = 0.f, aB2 = 0.f, aB3 = 0.f;
                int dd = 0;
                if (node < N_NODES) {
                    const int seg = rel * N_NODES + node;
                    int dtrue = cur[seg];
                    int d = min(dtrue, SLOT);
                    dd = dtrue;
                    const unsigned short* sb = slots + (size_t)seg * SLOT;
                    const float* xbp = x + (size_t)li * 8;
                    int i = 0;
                    for (; i + 4 <= d; i += 4) {
                        ushort4 s4 = *reinterpret_cast<const ushort4*>(sb + i);
                        const float* q0 = xbp + (size_t)s4.x * DIN;
                        const float* q1 = xbp + (size_t)s4.y * DIN;
                        const float* q2 = xbp + (size_t)s4.z * DIN;
                        const float* q3 = xbp + (size_t)s4.w * DIN;
                        float4 u0 = *reinterpret_cast<const float4*>(q0);
                        float4 w0 = *reinterpret_cast<const float4*>(q0 + 4);
                        float4 u1 = *reinterpret_cast<const float4*>(q1);
                        float4 w1 = *reinterpret_cast<const float4*>(q1 + 4);
                        float4 u2 = *reinterpret_cast<const float4*>(q2);
                        float4 w2 = *reinterpret_cast<const float4*>(q2 + 4);
                        float4 u3 = *reinterpret_cast<const float4*>(q3);
                        float4 w3 = *reinterpret_cast<const float4*>(q3 + 4);
                        aA0 += (u0.x + u1.x) + (u2.x + u3.x);
                        aA1 += (u0.y + u1.y) + (u2.y + u3.y);
                        aA2 += (u0.z + u1.z) + (u2.z + u3.z);
                        aA3 += (u0.w + u1.w) + (u2.w + u3.w);
                        aB0 += (w0.x + w1.x) + (w2.x + w3.x);
                        aB1 += (w0.y + w1.y) + (w2.y + w3.y);
                        aB2 += (w0.z + w1.z) + (w2.z + w3.z);
                        aB3 += (w0.w + w1.w) + (w2.w + w3.w);
                    }
                    for (; i < d; ++i) {
                        int s0 = sb[i];
                        const float* q0 = xbp + (size_t)s0 * DIN;
                        float4 u0 = *reinterpret_cast<const float4*>(q0);
                        float4 w0 = *reinterpret_cast<const float4*>(q0 + 4);
                        aA0 += u0.x; aA1 += u0.y; aA2 += u0.z; aA3 += u0.w;
                        aB0 += w0.x; aB1 += w0.y; aB2 += w0.z; aB3 += w0.w;
                    }
                }
                const float sc = 1.0f / (float)max(dd, 1);
                *reinterpret_cast<float4*>(&Ag[local][li * 8]) =
                    make_float4(aA0 * sc, aA1 * sc, aA2 * sc, aA3 * sc);
                *reinterpret_cast<float4*>(&Ag[local][li * 8 + 4]) =
                    make_float4(aB0 * sc, aB1 * sc, aB2 * sc, aB3 * sc);
            }
        } else {
#pragma unroll
            for (int j = 0; j < 8; ++j) {
                int idx = tid + j * 256;
                int row = idx >> 5;
                int q   = idx & 31;
                int node = mbase + row;
                float4 v = make_float4(0.f, 0.f, 0.f, 0.f);
                if (node < N_NODES)
                    v = *reinterpret_cast<const float4*>(x + (size_t)node * DIN + q * 4);
                *reinterpret_cast<float4*>(&Ag[row][q * 4]) = v;
            }
        }
        __syncthreads();

        const float* W = (rel == 0) ? W0 : (rel == 1) ? W1 : (rel == 2) ? W2 : Wl;
        for (int kc = 0; kc < 16; ++kc) {
            {
                int kk = tid >> 5;
                int cq = tid & 31;
                float4 v = *reinterpret_cast<const float4*>(W + (size_t)(kc * KB + kk) * DOUT + cq * 4);
                *reinterpret_cast<float4*>(&Bs[kk][cq * 4]) = v;
            }
            __syncthreads();
#pragma unroll
            for (int k = 0; k < KB; ++k) {
                float a[8], bb[4];
#pragma unroll
                for (int i = 0; i < 8; ++i) a[i] = Ag[rg * 8 + i][kc * KB + k];
                *reinterpret_cast<float4*>(&bb[0]) = *reinterpret_cast<const float4*>(&Bs[k][cg * 4]);
#pragma unroll
                for (int i = 0; i < 8; ++i)
#pragma unroll
                    for (int j = 0; j < 4; ++j) acc[i][j] += a[i] * bb[j];
            }
            __syncthreads();
        }
    }

    float4 bv = *reinterpret_cast<const float4*>(bias + cg * 4);
#pragma unroll
    for (int i = 0; i < 8; ++i) {
        int node = mbase + rg * 8 + i;
        if (node < N_NODES) {
            float4 o;
            o.x = fmaxf(acc[i][0] + bv.x, 0.f);
            o.y = fmaxf(acc[i][1] + bv.y, 0.f);
            o.z = fmaxf(acc[i][2] + bv.z, 0.f);
            o.w = fmaxf(acc[i][3] + bv.w, 0.f);
            *reinterpret_cast<float4*>(out + (size_t)node * DOUT + cg * 4) = o;
        }
    }
}

// ---------------------------------------------------------------------------
extern "C" void kernel_launch(void* const* d_in, const int* in_sizes, int n_in,
                              void* d_out, int out_size, void* d_ws, size_t ws_size,
                              hipStream_t stream) {
    const float* x    = (const float*)d_in[0];
    const int* src0   = (const int*)d_in[1];
    const int* dst0   = (const int*)d_in[2];
    const int* src1   = (const int*)d_in[3];
    const int* dst1   = (const int*)d_in[4];
    const int* src2   = (const int*)d_in[5];
    const int* dst2   = (const int*)d_in[6];
    const float* W0   = (const float*)d_in[7];
    const float* W1   = (const float*)d_in[8];
    const float* W2   = (const float*)d_in[9];
    const float* Wl   = (const float*)d_in[10];
    const float* bias = (const float*)d_in[11];
    float* out        = (float*)d_out;

    // layout: cur 600KB | slots 12MB | xb 12.8MB | aggb 38.4MB  (~63.9MB)
    const size_t sz_cur   = (size_t)NREL * N_NODES * sizeof(int);
    const size_t sz_slots = (size_t)NREL * N_NODES * SLOT * sizeof(unsigned short);
    const size_t sz_xb    = (size_t)N_NODES * DIN * sizeof(unsigned short);
    const size_t sz_aggb  = (size_t)NREL * N_NODES * DIN * sizeof(unsigned short);

    char* p = (char*)d_ws;
    int* cur = (int*)p;                       p += (sz_cur + 255) & ~(size_t)255;
    unsigned short* slots = (unsigned short*)p; p += (sz_slots + 255) & ~(size_t)255;
    unsigned short* xb    = (unsigned short*)p; p += (sz_xb + 255) & ~(size_t)255;
    unsigned short* aggb  = (unsigned short*)p; p += (sz_aggb + 255) & ~(size_t)255;
    const size_t need = (size_t)(p - (char*)d_ws);

    hipMemsetAsync(cur, 0, sz_cur, stream);

    const int eb = (E_EDGES + 255) / 256;
    k_fill_direct<<<eb, 256, 0, stream>>>(src0, dst0, src1, dst1, src2, dst2, cur, slots);

    if (ws_size >= need) {
        k_xcast<<<(N_NODES * DIN / 8 + 255) / 256, 256, 0, stream>>>(x, xb);
        k_gather<<<NREL * NB, 256, 0, stream>>>(xb, cur, slots, aggb);
        k_gemm<<<NB, 256, 0, stream>>>(x, aggb, W0, W1, W2, Wl, bias, out);
    } else {
        k_fused_fb<<<NB, 256, 0, stream>>>(x, cur, slots, W0, W1, W2, Wl, bias, out);
    }
}

// Round 10
// 290.962 us; speedup vs baseline: 6.0093x; 1.3009x over previous
//
#include <hip/hip_runtime.h>
#include <hip/hip_bf16.h>

#define N_NODES 50000
#define E_EDGES 500000
#define NREL    3
#define DIN     128
#define DOUT    128
#define SLOT    40    // max in-degree per (rel,node); Poisson(10) tail P(exceed) ~ 1e-8 total
#define NB      782   // ceil(N_NODES / 64)
#define BM      64
#define KB      8

typedef __attribute__((ext_vector_type(8))) short bf16x8;
typedef __attribute__((ext_vector_type(4))) float f32x4;

// ---- bf16 helpers (RNE pack, shift unpack) --------------------------------
__device__ __forceinline__ unsigned int f2bf(float f) {
    unsigned int u = __float_as_uint(f);
    unsigned int r = (u + 0x7FFFu + ((u >> 16) & 1u)) >> 16;
    return r;
}
__device__ __forceinline__ float bf2f_lo(unsigned int u) { return __uint_as_float(u << 16); }
__device__ __forceinline__ float bf2f_hi(unsigned int u) { return __uint_as_float(u & 0xFFFF0000u); }

// ---------------------------------------------------------------------------
// Phase 1: bin edges into per-(rel,node) fixed slots. cur[seg] ends as
// in-degree; slots[seg*SLOT + 0..deg) hold u16 srcs.
// ---------------------------------------------------------------------------
__global__ __launch_bounds__(256) void k_fill_direct(const int* __restrict__ src0,
                                                     const int* __restrict__ dst0,
                                                     const int* __restrict__ src1,
                                                     const int* __restrict__ dst1,
                                                     const int* __restrict__ src2,
                                                     const int* __restrict__ dst2,
                                                     int* __restrict__ cur,
                                                     unsigned short* __restrict__ slots) {
    int e = blockIdx.x * 256 + threadIdx.x;
    if (e >= E_EDGES) return;

    int d0 = dst0[e];
    int p0 = atomicAdd(&cur[0 * N_NODES + d0], 1);
    if (p0 < SLOT) slots[(size_t)(0 * N_NODES + d0) * SLOT + p0] = (unsigned short)src0[e];

    int d1 = dst1[e];
    int p1 = atomicAdd(&cur[1 * N_NODES + d1], 1);
    if (p1 < SLOT) slots[(size_t)(1 * N_NODES + d1) * SLOT + p1] = (unsigned short)src1[e];

    int d2 = dst2[e];
    int p2 = atomicAdd(&cur[2 * N_NODES + d2], 1);
    if (p2 < SLOT) slots[(size_t)(2 * N_NODES + d2) * SLOT + p2] = (unsigned short)src2[e];
}

// ---------------------------------------------------------------------------
// Phase 2a: cast x to bf16. 8 floats / thread.
// ---------------------------------------------------------------------------
__global__ __launch_bounds__(256) void k_xcast(const float* __restrict__ x,
                                               unsigned short* __restrict__ xb) {
    int i = (blockIdx.x * 256 + threadIdx.x) * 8;
    if (i >= N_NODES * DIN) return;
    float4 a = *reinterpret_cast<const float4*>(x + i);
    float4 b = *reinterpret_cast<const float4*>(x + i + 4);
    uint4 o;
    o.x = f2bf(a.x) | (f2bf(a.y) << 16);
    o.y = f2bf(a.z) | (f2bf(a.w) << 16);
    o.z = f2bf(b.x) | (f2bf(b.y) << 16);
    o.w = f2bf(b.z) | (f2bf(b.w) << 16);
    *reinterpret_cast<uint4*>(xb + i) = o;
}

// ---------------------------------------------------------------------------
// Phase 2b: cast+transpose W: Wtb[rel][c][k] = bf16(W_rel[k][c]).
// One thread per output element, k fastest -> coalesced u16 writes.
// ---------------------------------------------------------------------------
__global__ __launch_bounds__(256) void k_wcast(const float* __restrict__ W0,
                                               const float* __restrict__ W1,
                                               const float* __restrict__ W2,
                                               const float* __restrict__ Wl,
                                               unsigned short* __restrict__ Wtb) {
    int t = blockIdx.x * 256 + threadIdx.x;        // 0 .. 4*128*128-1
    if (t >= 4 * DIN * DOUT) return;
    int k   = t & 127;
    int c   = (t >> 7) & 127;
    int rel = t >> 14;
    const float* W = (rel == 0) ? W0 : (rel == 1) ? W1 : (rel == 2) ? W2 : Wl;
    Wtb[t] = (unsigned short)f2bf(W[(size_t)k * DOUT + c]);
}

// ---------------------------------------------------------------------------
// Phase 3: gather-aggregate (unchanged from round 9).
// ---------------------------------------------------------------------------
__global__ __launch_bounds__(256) void k_gather(const unsigned short* __restrict__ xb,
                                                const int* __restrict__ cur,
                                                const unsigned short* __restrict__ slots,
                                                unsigned short* __restrict__ aggb) {
    const int rel  = blockIdx.x / NB;
    const int blk  = blockIdx.x % NB;
    const int mbase = blk * BM;
    const int tid  = threadIdx.x;
    const int wave = tid >> 6;
    const int lane = tid & 63;
    const int g    = lane >> 4;
    const int li   = lane & 15;

#pragma unroll
    for (int t = 0; t < 4; ++t) {
        const int local = wave * 16 + g * 4 + t;
        const int node  = mbase + local;
        if (node >= N_NODES) continue;
        const int seg = rel * N_NODES + node;
        const int dtrue = cur[seg];
        const int d = min(dtrue, SLOT);
        const unsigned short* sb = slots + (size_t)seg * SLOT;
        const unsigned short* xbb = xb + (size_t)li * 8;

        float acc[8];
#pragma unroll
        for (int k = 0; k < 8; ++k) acc[k] = 0.f;

        int i = 0;
        for (; i + 4 <= d; i += 4) {
            ushort4 s4 = *reinterpret_cast<const ushort4*>(sb + i);
            uint4 u0 = *reinterpret_cast<const uint4*>(xbb + (size_t)s4.x * DIN);
            uint4 u1 = *reinterpret_cast<const uint4*>(xbb + (size_t)s4.y * DIN);
            uint4 u2 = *reinterpret_cast<const uint4*>(xbb + (size_t)s4.z * DIN);
            uint4 u3 = *reinterpret_cast<const uint4*>(xbb + (size_t)s4.w * DIN);
            acc[0] += bf2f_lo(u0.x) + bf2f_lo(u1.x) + bf2f_lo(u2.x) + bf2f_lo(u3.x);
            acc[1] += bf2f_hi(u0.x) + bf2f_hi(u1.x) + bf2f_hi(u2.x) + bf2f_hi(u3.x);
            acc[2] += bf2f_lo(u0.y) + bf2f_lo(u1.y) + bf2f_lo(u2.y) + bf2f_lo(u3.y);
            acc[3] += bf2f_hi(u0.y) + bf2f_hi(u1.y) + bf2f_hi(u2.y) + bf2f_hi(u3.y);
            acc[4] += bf2f_lo(u0.z) + bf2f_lo(u1.z) + bf2f_lo(u2.z) + bf2f_lo(u3.z);
            acc[5] += bf2f_hi(u0.z) + bf2f_hi(u1.z) + bf2f_hi(u2.z) + bf2f_hi(u3.z);
            acc[6] += bf2f_lo(u0.w) + bf2f_lo(u1.w) + bf2f_lo(u2.w) + bf2f_lo(u3.w);
            acc[7] += bf2f_hi(u0.w) + bf2f_hi(u1.w) + bf2f_hi(u2.w) + bf2f_hi(u3.w);
        }
        for (; i < d; ++i) {
            uint4 u0 = *reinterpret_cast<const uint4*>(xbb + (size_t)sb[i] * DIN);
            acc[0] += bf2f_lo(u0.x); acc[1] += bf2f_hi(u0.x);
            acc[2] += bf2f_lo(u0.y); acc[3] += bf2f_hi(u0.y);
            acc[4] += bf2f_lo(u0.z); acc[5] += bf2f_hi(u0.z);
            acc[6] += bf2f_lo(u0.w); acc[7] += bf2f_hi(u0.w);
        }

        const float inv = 1.0f / (float)max(dtrue, 1);
        uint4 o;
        o.x = f2bf(acc[0] * inv) | (f2bf(acc[1] * inv) << 16);
        o.y = f2bf(acc[2] * inv) | (f2bf(acc[3] * inv) << 16);
        o.z = f2bf(acc[4] * inv) | (f2bf(acc[5] * inv) << 16);
        o.w = f2bf(acc[6] * inv) | (f2bf(acc[7] * inv) << 16);
        *reinterpret_cast<uint4*>(aggb + (size_t)seg * DIN + li * 8) = o;
    }
}

// ---------------------------------------------------------------------------
// Phase 4: MFMA GEMM.  out = relu(concat(agg0..2, x)_bf16 @ W_bf16 + b).
// 4 waves/block, BM=64 (16 rows/wave), N=128 (8 col-tiles), K=512.
// Per rel: stage A[64][128] and Wt[128][128] bf16 tiles into LDS (rows
// padded to 136 bf16 -> 272B stride -> frag reads 2-way bank-aliased = free).
// Fragments (m89/m92/m97-verified layout):
//   a[r]   = A[l&15][8*(l>>4)+r]        (contiguous bf16x8 from a row)
//   b[r]   = Wt[ct*16+(l&15)][8*(l>>4)+r]
//   acc: C[row=(l>>4)*4+reg][col=ct*16+(l&15)]
// ---------------------------------------------------------------------------
__global__ __launch_bounds__(256) void k_gemm_mfma(const unsigned short* __restrict__ xb,
                                                   const unsigned short* __restrict__ aggb,
                                                   const unsigned short* __restrict__ Wtb,
                                                   const float* __restrict__ bias,
                                                   float* __restrict__ out) {
    __shared__ unsigned short At[BM][136];    // 17.4 KB
    __shared__ unsigned short Bt[DOUT][136];  // 34.8 KB

    const int tid   = threadIdx.x;
    const int mbase = blockIdx.x * BM;
    const int w     = tid >> 6;       // wave 0..3 -> rows w*16..w*16+15
    const int l     = tid & 63;
    const int lr    = l & 15;         // row-in-frag / col-in-frag
    const int lk    = l >> 4;         // k-group 0..3

    f32x4 acc[8];
#pragma unroll
    for (int ct = 0; ct < 8; ++ct) acc[ct] = (f32x4){0.f, 0.f, 0.f, 0.f};

    for (int rel = 0; rel < 4; ++rel) {
        __syncthreads();   // previous iter's frag reads done before overwrite

        // stage A tile: 64 rows x 128 k, 1024 x 16B, 4 per thread
        const unsigned short* Asrc = (rel < 3) ? (aggb + (size_t)rel * N_NODES * DIN) : xb;
#pragma unroll
        for (int j = 0; j < 4; ++j) {
            int idx = tid + j * 256;          // 0..1023
            int row = idx >> 4;               // 0..63
            int oct = idx & 15;               // k-offset oct*8
            int node = mbase + row;
            int nc = node < N_NODES ? node : N_NODES - 1;
            uint4 u = *reinterpret_cast<const uint4*>(Asrc + (size_t)nc * DIN + oct * 8);
            *reinterpret_cast<uint4*>(&At[row][oct * 8]) = u;
        }
        // stage Wt tile: 128 cols x 128 k, 2048 x 16B, 8 per thread
        const unsigned short* Bsrc = Wtb + (size_t)rel * DIN * DOUT;
#pragma unroll
        for (int j = 0; j < 8; ++j) {
            int idx = tid + j * 256;          // 0..2047
            int c   = idx >> 4;               // 0..127
            int oct = idx & 15;
            uint4 u = *reinterpret_cast<const uint4*>(Bsrc + (size_t)c * DIN + oct * 8);
            *reinterpret_cast<uint4*>(&Bt[c][oct * 8]) = u;
        }
        __syncthreads();

#pragma unroll
        for (int kc = 0; kc < 4; ++kc) {      // K-steps of 32
            bf16x8 a = *reinterpret_cast<const bf16x8*>(&At[w * 16 + lr][kc * 32 + lk * 8]);
#pragma unroll
            for (int ct = 0; ct < 8; ++ct) {
                bf16x8 b = *reinterpret_cast<const bf16x8*>(&Bt[ct * 16 + lr][kc * 32 + lk * 8]);
                acc[ct] = __builtin_amdgcn_mfma_f32_16x16x32_bf16(a, b, acc[ct], 0, 0, 0);
            }
        }
    }

    // epilogue: bias + relu
#pragma unroll
    for (int ct = 0; ct < 8; ++ct) {
        int col = ct * 16 + lr;
        float bv = bias[col];
#pragma unroll
        for (int r = 0; r < 4; ++r) {
            int row = mbase + w * 16 + lk * 4 + r;
            if (row < N_NODES)
                out[(size_t)row * DOUT + col] = fmaxf(acc[ct][r] + bv, 0.f);
        }
    }
}

// ---------------------------------------------------------------------------
// Fallback fused kernel (round-6 structure): used if ws too small.
// ---------------------------------------------------------------------------
__global__ __launch_bounds__(256) void k_fused_fb(const float* __restrict__ x,
                                                  const int* __restrict__ cur,
                                                  const unsigned short* __restrict__ slots,
                                                  const float* __restrict__ W0,
                                                  const float* __restrict__ W1,
                                                  const float* __restrict__ W2,
                                                  const float* __restrict__ Wl,
                                                  const float* __restrict__ bias,
                                                  float* __restrict__ out) {
    __shared__ float Ag[BM][132];
    __shared__ float Bs[KB][DOUT];

    const int tid   = threadIdx.x;
    const int mbase = blockIdx.x * BM;
    const int wave  = tid >> 6;
    const int lane  = tid & 63;
    const int g     = lane >> 4;
    const int li    = lane & 15;
    const int rg    = tid >> 5;
    const int cg    = tid & 31;

    float acc[8][4];
#pragma unroll
    for (int i = 0; i < 8; ++i)
#pragma unroll
        for (int j = 0; j < 4; ++j) acc[i][j] = 0.f;

    for (int rel = 0; rel < 4; ++rel) {
        __syncthreads();
        if (rel < 3) {
#pragma unroll
            for (int t = 0; t < 4; ++t) {
                const int local = wave * 16 + g * 4 + t;
                const int node  = mbase + local;
                float aA0 = 0.f, aA1 = 0.f, aA2 = 0.f, aA3 = 0.f;
                float aB0 = 0.f, aB1 = 0.f, aB2 = 0.f, aB3 = 0.f;
                int dd = 0;
                if (node < N_NODES) {
                    const int seg = rel * N_NODES + node;
                    int dtrue = cur[seg];
                    int d = min(dtrue, SLOT);
                    dd = dtrue;
                    const unsigned short* sb = slots + (size_t)seg * SLOT;
                    const float* xbp = x + (size_t)li * 8;
                    int i = 0;
                    for (; i + 4 <= d; i += 4) {
                        ushort4 s4 = *reinterpret_cast<const ushort4*>(sb + i);
                        const float* q0 = xbp + (size_t)s4.x * DIN;
                        const float* q1 = xbp + (size_t)s4.y * DIN;
                        const float* q2 = xbp + (size_t)s4.z * DIN;
                        const float* q3 = xbp + (size_t)s4.w * DIN;
                        float4 u0 = *reinterpret_cast<const float4*>(q0);
                        float4 w0 = *reinterpret_cast<const float4*>(q0 + 4);
                        float4 u1 = *reinterpret_cast<const float4*>(q1);
                        float4 w1 = *reinterpret_cast<const float4*>(q1 + 4);
                        float4 u2 = *reinterpret_cast<const float4*>(q2);
                        float4 w2 = *reinterpret_cast<const float4*>(q2 + 4);
                        float4 u3 = *reinterpret_cast<const float4*>(q3);
                        float4 w3 = *reinterpret_cast<const float4*>(q3 + 4);
                        aA0 += (u0.x + u1.x) + (u2.x + u3.x);
                        aA1 += (u0.y + u1.y) + (u2.y + u3.y);
                        aA2 += (u0.z + u1.z) + (u2.z + u3.z);
                        aA3 += (u0.w + u1.w) + (u2.w + u3.w);
                        aB0 += (w0.x + w1.x) + (w2.x + w3.x);
                        aB1 += (w0.y + w1.y) + (w2.y + w3.y);
                        aB2 += (w0.z + w1.z) + (w2.z + w3.z);
                        aB3 += (w0.w + w1.w) + (w2.w + w3.w);
                    }
                    for (; i < d; ++i) {
                        int s0 = sb[i];
                        const float* q0 = xbp + (size_t)s0 * DIN;
                        float4 u0 = *reinterpret_cast<const float4*>(q0);
                        float4 w0 = *reinterpret_cast<const float4*>(q0 + 4);
                        aA0 += u0.x; aA1 += u0.y; aA2 += u0.z; aA3 += u0.w;
                        aB0 += w0.x; aB1 += w0.y; aB2 += w0.z; aB3 += w0.w;
                    }
                }
                const float sc = 1.0f / (float)max(dd, 1);
                *reinterpret_cast<float4*>(&Ag[local][li * 8]) =
                    make_float4(aA0 * sc, aA1 * sc, aA2 * sc, aA3 * sc);
                *reinterpret_cast<float4*>(&Ag[local][li * 8 + 4]) =
                    make_float4(aB0 * sc, aB1 * sc, aB2 * sc, aB3 * sc);
            }
        } else {
#pragma unroll
            for (int j = 0; j < 8; ++j) {
                int idx = tid + j * 256;
                int row = idx >> 5;
                int q   = idx & 31;
                int node = mbase + row;
                float4 v = make_float4(0.f, 0.f, 0.f, 0.f);
                if (node < N_NODES)
                    v = *reinterpret_cast<const float4*>(x + (size_t)node * DIN + q * 4);
                *reinterpret_cast<float4*>(&Ag[row][q * 4]) = v;
            }
        }
        __syncthreads();

        const float* W = (rel == 0) ? W0 : (rel == 1) ? W1 : (rel == 2) ? W2 : Wl;
        for (int kc = 0; kc < 16; ++kc) {
            {
                int kk = tid >> 5;
                int cq = tid & 31;
                float4 v = *reinterpret_cast<const float4*>(W + (size_t)(kc * KB + kk) * DOUT + cq * 4);
                *reinterpret_cast<float4*>(&Bs[kk][cq * 4]) = v;
            }
            __syncthreads();
#pragma unroll
            for (int k = 0; k < KB; ++k) {
                float a[8], bb[4];
#pragma unroll
                for (int i = 0; i < 8; ++i) a[i] = Ag[rg * 8 + i][kc * KB + k];
                *reinterpret_cast<float4*>(&bb[0]) = *reinterpret_cast<const float4*>(&Bs[k][cg * 4]);
#pragma unroll
                for (int i = 0; i < 8; ++i)
#pragma unroll
                    for (int j = 0; j < 4; ++j) acc[i][j] += a[i] * bb[j];
            }
            __syncthreads();
        }
    }

    float4 bv = *reinterpret_cast<const float4*>(bias + cg * 4);
#pragma unroll
    for (int i = 0; i < 8; ++i) {
        int node = mbase + rg * 8 + i;
        if (node < N_NODES) {
            float4 o;
            o.x = fmaxf(acc[i][0] + bv.x, 0.f);
            o.y = fmaxf(acc[i][1] + bv.y, 0.f);
            o.z = fmaxf(acc[i][2] + bv.z, 0.f);
            o.w = fmaxf(acc[i][3] + bv.w, 0.f);
            *reinterpret_cast<float4*>(out + (size_t)node * DOUT + cg * 4) = o;
        }
    }
}

// ---------------------------------------------------------------------------
extern "C" void kernel_launch(void* const* d_in, const int* in_sizes, int n_in,
                              void* d_out, int out_size, void* d_ws, size_t ws_size,
                              hipStream_t stream) {
    const float* x    = (const float*)d_in[0];
    const int* src0   = (const int*)d_in[1];
    const int* dst0   = (const int*)d_in[2];
    const int* src1   = (const int*)d_in[3];
    const int* dst1   = (const int*)d_in[4];
    const int* src2   = (const int*)d_in[5];
    const int* dst2   = (const int*)d_in[6];
    const float* W0   = (const float*)d_in[7];
    const float* W1   = (const float*)d_in[8];
    const float* W2   = (const float*)d_in[9];
    const float* Wl   = (const float*)d_in[10];
    const float* bias = (const float*)d_in[11];
    float* out        = (float*)d_out;

    // layout: cur 600KB | slots 12MB | xb 12.8MB | aggb 38.4MB | Wtb 128KB
    const size_t sz_cur   = (size_t)NREL * N_NODES * sizeof(int);
    const size_t sz_slots = (size_t)NREL * N_NODES * SLOT * sizeof(unsigned short);
    const size_t sz_xb    = (size_t)N_NODES * DIN * sizeof(unsigned short);
    const size_t sz_aggb  = (size_t)NREL * N_NODES * DIN * sizeof(unsigned short);
    const size_t sz_wtb   = (size_t)4 * DIN * DOUT * sizeof(unsigned short);

    char* p = (char*)d_ws;
    int* cur = (int*)p;                         p += (sz_cur + 255) & ~(size_t)255;
    unsigned short* slots = (unsigned short*)p; p += (sz_slots + 255) & ~(size_t)255;
    unsigned short* xb    = (unsigned short*)p; p += (sz_xb + 255) & ~(size_t)255;
    unsigned short* aggb  = (unsigned short*)p; p += (sz_aggb + 255) & ~(size_t)255;
    unsigned short* Wtb   = (unsigned short*)p; p += (sz_wtb + 255) & ~(size_t)255;
    const size_t need = (size_t)(p - (char*)d_ws);

    hipMemsetAsync(cur, 0, sz_cur, stream);

    const int eb = (E_EDGES + 255) / 256;
    k_fill_direct<<<eb, 256, 0, stream>>>(src0, dst0, src1, dst1, src2, dst2, cur, slots);

    if (ws_size >= need) {
        k_xcast<<<(N_NODES * DIN / 8 + 255) / 256, 256, 0, stream>>>(x, xb);
        k_wcast<<<(4 * DIN * DOUT + 255) / 256, 256, 0, stream>>>(W0, W1, W2, Wl, Wtb);
        k_gather<<<NREL * NB, 256, 0, stream>>>(xb, cur, slots, aggb);
        k_gemm_mfma<<<NB, 256, 0, stream>>>(xb, aggb, Wtb, bias, out);
    } else {
        k_fused_fb<<<NB, 256, 0, stream>>>(x, cur, slots, W0, W1, W2, Wl, bias, out);
    }
}

// Round 11
// 205.988 us; speedup vs baseline: 8.4883x; 1.4125x over previous
//
#include <hip/hip_runtime.h>
#include <hip/hip_bf16.h>

#define N_NODES 50000
#define E_EDGES 500000
#define NREL    3
#define DIN     128
#define DOUT    128
#define SLOT    40    // max in-degree per (rel,node); Poisson(10) tail P(exceed) ~ 1e-8 total
#define NB      782   // ceil(N_NODES / 64) == bins per rel
#define BM      64
#define KB      8
#define CAP     1024  // entries per (rel,dst-block) bin; E[fill]=640, +15 sigma
#define BUFW    16    // LDS flush group = 16 u32 = 64B
#define NCHUNK  170   // edge chunks per rel in k_binfill (510 blocks total)

typedef __attribute__((ext_vector_type(8))) short bf16x8;
typedef __attribute__((ext_vector_type(4))) float f32x4;

// ---- bf16 helpers (RNE pack, shift unpack) --------------------------------
__device__ __forceinline__ unsigned int f2bf(float f) {
    unsigned int u = __float_as_uint(f);
    unsigned int r = (u + 0x7FFFu + ((u >> 16) & 1u)) >> 16;
    return r;
}
__device__ __forceinline__ float bf2f_lo(unsigned int u) { return __uint_as_float(u << 16); }
__device__ __forceinline__ float bf2f_hi(unsigned int u) { return __uint_as_float(u & 0xFFFF0000u); }

// ---------------------------------------------------------------------------
// Phase 1: radix-partition edges into (rel, dst>>6) bins with LDS-buffered
// 64B-dense flushes. Entry = (src << 6) | (dst & 63). Cuts HBM write
// amplification 90MB -> ~6MB (round-10 counter evidence: k_fill_direct was
// write-scatter-bound, WRITE_SIZE 90MB, VALUBusy 0.35%).
// ---------------------------------------------------------------------------
__global__ __launch_bounds__(256) void k_binfill(const int* __restrict__ src0,
                                                 const int* __restrict__ dst0,
                                                 const int* __restrict__ src1,
                                                 const int* __restrict__ dst1,
                                                 const int* __restrict__ src2,
                                                 const int* __restrict__ dst2,
                                                 int* __restrict__ gcnt,
                                                 unsigned int* __restrict__ bins) {
    __shared__ unsigned int buf[NB][BUFW];   // 50.0 KB
    __shared__ int cnt[NB];                  // 3.1 KB
    __shared__ int flushed[NB];              // 3.1 KB

    const int tid   = threadIdx.x;
    const int rel   = blockIdx.x / NCHUNK;
    const int chunk = blockIdx.x % NCHUNK;
    const int EPB   = (E_EDGES + NCHUNK - 1) / NCHUNK;   // 2942
    const int base  = chunk * EPB;
    const int eend  = min(base + EPB, E_EDGES);

    const int* srcp = (rel == 0) ? src0 : (rel == 1) ? src1 : src2;
    const int* dstp = (rel == 0) ? dst0 : (rel == 1) ? dst1 : dst2;

    for (int b = tid; b < NB; b += 256) { cnt[b] = 0; flushed[b] = 0; }
    __syncthreads();

    for (int it = base; it < eend; it += 256) {
        int e = it + tid;
        if (e < eend) {
            int d = dstp[e];
            int s = srcp[e];
            int bin = d >> 6;
            unsigned int entry = ((unsigned int)s << 6) | (unsigned int)(d & 63);
            int pos = atomicAdd(&cnt[bin], 1);
            if (pos - flushed[bin] < BUFW) {
                buf[bin][pos & (BUFW - 1)] = entry;
            } else {
                // rare intra-iteration overflow: direct scatter
                int g = atomicAdd(&gcnt[rel * NB + bin], 1);
                if (g < CAP) bins[(size_t)(rel * NB + bin) * CAP + g] = entry;
            }
        }
        __syncthreads();
        // flush full 16-entry groups (one owner thread per bin)
        for (int b = tid; b < NB; b += 256) {
            while (cnt[b] - flushed[b] >= BUFW) {
                int f = flushed[b];
                int g = atomicAdd(&gcnt[rel * NB + b], BUFW);
                unsigned int* gp = bins + (size_t)(rel * NB + b) * CAP;
#pragma unroll
                for (int i = 0; i < BUFW; ++i) {
                    if (g + i < CAP) gp[g + i] = buf[b][(f + i) & (BUFW - 1)];
                }
                flushed[b] = f + BUFW;
            }
        }
        __syncthreads();
    }
    // final partial flush
    for (int b = tid; b < NB; b += 256) {
        int c = cnt[b], f = flushed[b];
        if (c > f) {
            int n = c - f;
            int g = atomicAdd(&gcnt[rel * NB + b], n);
            unsigned int* gp = bins + (size_t)(rel * NB + b) * CAP;
            for (int i = 0; i < n; ++i)
                if (g + i < CAP) gp[g + i] = buf[b][(f + i) & (BUFW - 1)];
        }
    }
}

// ---------------------------------------------------------------------------
// Phase 2a: cast x to bf16. 8 floats / thread.
// ---------------------------------------------------------------------------
__global__ __launch_bounds__(256) void k_xcast(const float* __restrict__ x,
                                               unsigned short* __restrict__ xb) {
    int i = (blockIdx.x * 256 + threadIdx.x) * 8;
    if (i >= N_NODES * DIN) return;
    float4 a = *reinterpret_cast<const float4*>(x + i);
    float4 b = *reinterpret_cast<const float4*>(x + i + 4);
    uint4 o;
    o.x = f2bf(a.x) | (f2bf(a.y) << 16);
    o.y = f2bf(a.z) | (f2bf(a.w) << 16);
    o.z = f2bf(b.x) | (f2bf(b.y) << 16);
    o.w = f2bf(b.z) | (f2bf(b.w) << 16);
    *reinterpret_cast<uint4*>(xb + i) = o;
}

// ---------------------------------------------------------------------------
// Phase 2b: cast+transpose W: Wtb[rel][c][k] = bf16(W_rel[k][c]).
// ---------------------------------------------------------------------------
__global__ __launch_bounds__(256) void k_wcast(const float* __restrict__ W0,
                                               const float* __restrict__ W1,
                                               const float* __restrict__ W2,
                                               const float* __restrict__ Wl,
                                               unsigned short* __restrict__ Wtb) {
    int t = blockIdx.x * 256 + threadIdx.x;
    if (t >= 4 * DIN * DOUT) return;
    int k   = t & 127;
    int c   = (t >> 7) & 127;
    int rel = t >> 14;
    const float* W = (rel == 0) ? W0 : (rel == 1) ? W1 : (rel == 2) ? W2 : Wl;
    Wtb[t] = (unsigned short)f2bf(W[(size_t)k * DOUT + c]);
}

// ---------------------------------------------------------------------------
// Phase 3: gather-aggregate with in-LDS per-node binning. One block per
// (rel, 64-node block): read this bin's packed entries (dense, coalesced),
// scatter to per-node u16 src-lists in LDS (int LDS atomics, native), then
// aggregate per node (16-lane groups, bf16 rows, fp32 accum) and store bf16.
// ---------------------------------------------------------------------------
__global__ __launch_bounds__(256) void k_gather(const unsigned short* __restrict__ xb,
                                                const int* __restrict__ gcnt,
                                                const unsigned int* __restrict__ bins,
                                                unsigned short* __restrict__ aggb) {
    __shared__ unsigned short lists[BM][SLOT];   // 5.0 KB
    __shared__ int dcnt[BM];

    const int rel   = blockIdx.x / NB;
    const int blk   = blockIdx.x % NB;
    const int mbase = blk * BM;
    const int tid   = threadIdx.x;
    const int wave  = tid >> 6;
    const int lane  = tid & 63;
    const int g     = lane >> 4;
    const int li    = lane & 15;      // covers feats li*8 .. li*8+7

    if (tid < BM) dcnt[tid] = 0;
    __syncthreads();

    const int bin = rel * NB + blk;
    const int n   = min(gcnt[bin], CAP);
    const unsigned int* bp = bins + (size_t)bin * CAP;
    for (int i = tid; i < n; i += 256) {
        unsigned int e = bp[i];
        int lo = (int)(e & 63u);
        int s  = (int)(e >> 6);
        int pos = atomicAdd(&dcnt[lo], 1);
        if (pos < SLOT) lists[lo][pos] = (unsigned short)s;
    }
    __syncthreads();

#pragma unroll
    for (int t = 0; t < 4; ++t) {
        const int local = wave * 16 + g * 4 + t;
        const int node  = mbase + local;
        if (node >= N_NODES) continue;
        const int dtrue = dcnt[local];
        const int d = min(dtrue, SLOT);
        const unsigned short* sb = &lists[local][0];
        const unsigned short* xbb = xb + (size_t)li * 8;

        float acc[8];
#pragma unroll
        for (int k = 0; k < 8; ++k) acc[k] = 0.f;

        int i = 0;
        for (; i + 4 <= d; i += 4) {
            ushort4 s4 = *reinterpret_cast<const ushort4*>(sb + i);   // LDS broadcast
            uint4 u0 = *reinterpret_cast<const uint4*>(xbb + (size_t)s4.x * DIN);
            uint4 u1 = *reinterpret_cast<const uint4*>(xbb + (size_t)s4.y * DIN);
            uint4 u2 = *reinterpret_cast<const uint4*>(xbb + (size_t)s4.z * DIN);
            uint4 u3 = *reinterpret_cast<const uint4*>(xbb + (size_t)s4.w * DIN);
            acc[0] += bf2f_lo(u0.x) + bf2f_lo(u1.x) + bf2f_lo(u2.x) + bf2f_lo(u3.x);
            acc[1] += bf2f_hi(u0.x) + bf2f_hi(u1.x) + bf2f_hi(u2.x) + bf2f_hi(u3.x);
            acc[2] += bf2f_lo(u0.y) + bf2f_lo(u1.y) + bf2f_lo(u2.y) + bf2f_lo(u3.y);
            acc[3] += bf2f_hi(u0.y) + bf2f_hi(u1.y) + bf2f_hi(u2.y) + bf2f_hi(u3.y);
            acc[4] += bf2f_lo(u0.z) + bf2f_lo(u1.z) + bf2f_lo(u2.z) + bf2f_lo(u3.z);
            acc[5] += bf2f_hi(u0.z) + bf2f_hi(u1.z) + bf2f_hi(u2.z) + bf2f_hi(u3.z);
            acc[6] += bf2f_lo(u0.w) + bf2f_lo(u1.w) + bf2f_lo(u2.w) + bf2f_lo(u3.w);
            acc[7] += bf2f_hi(u0.w) + bf2f_hi(u1.w) + bf2f_hi(u2.w) + bf2f_hi(u3.w);
        }
        for (; i < d; ++i) {
            uint4 u0 = *reinterpret_cast<const uint4*>(xbb + (size_t)sb[i] * DIN);
            acc[0] += bf2f_lo(u0.x); acc[1] += bf2f_hi(u0.x);
            acc[2] += bf2f_lo(u0.y); acc[3] += bf2f_hi(u0.y);
            acc[4] += bf2f_lo(u0.z); acc[5] += bf2f_hi(u0.z);
            acc[6] += bf2f_lo(u0.w); acc[7] += bf2f_hi(u0.w);
        }

        const float inv = 1.0f / (float)max(dtrue, 1);
        uint4 o;
        o.x = f2bf(acc[0] * inv) | (f2bf(acc[1] * inv) << 16);
        o.y = f2bf(acc[2] * inv) | (f2bf(acc[3] * inv) << 16);
        o.z = f2bf(acc[4] * inv) | (f2bf(acc[5] * inv) << 16);
        o.w = f2bf(acc[6] * inv) | (f2bf(acc[7] * inv) << 16);
        *reinterpret_cast<uint4*>(aggb + (size_t)(rel * N_NODES + node) * DIN + li * 8) = o;
    }
}

// ---------------------------------------------------------------------------
// Phase 4: MFMA GEMM (validated round 10, unchanged).
// ---------------------------------------------------------------------------
__global__ __launch_bounds__(256) void k_gemm_mfma(const unsigned short* __restrict__ xb,
                                                   const unsigned short* __restrict__ aggb,
                                                   const unsigned short* __restrict__ Wtb,
                                                   const float* __restrict__ bias,
                                                   float* __restrict__ out) {
    __shared__ unsigned short At[BM][136];    // 17.4 KB
    __shared__ unsigned short Bt[DOUT][136];  // 34.8 KB

    const int tid   = threadIdx.x;
    const int mbase = blockIdx.x * BM;
    const int w     = tid >> 6;
    const int l     = tid & 63;
    const int lr    = l & 15;
    const int lk    = l >> 4;

    f32x4 acc[8];
#pragma unroll
    for (int ct = 0; ct < 8; ++ct) acc[ct] = (f32x4){0.f, 0.f, 0.f, 0.f};

    for (int rel = 0; rel < 4; ++rel) {
        __syncthreads();

        const unsigned short* Asrc = (rel < 3) ? (aggb + (size_t)rel * N_NODES * DIN) : xb;
#pragma unroll
        for (int j = 0; j < 4; ++j) {
            int idx = tid + j * 256;
            int row = idx >> 4;
            int oct = idx & 15;
            int node = mbase + row;
            int nc = node < N_NODES ? node : N_NODES - 1;
            uint4 u = *reinterpret_cast<const uint4*>(Asrc + (size_t)nc * DIN + oct * 8);
            *reinterpret_cast<uint4*>(&At[row][oct * 8]) = u;
        }
        const unsigned short* Bsrc = Wtb + (size_t)rel * DIN * DOUT;
#pragma unroll
        for (int j = 0; j < 8; ++j) {
            int idx = tid + j * 256;
            int c   = idx >> 4;
            int oct = idx & 15;
            uint4 u = *reinterpret_cast<const uint4*>(Bsrc + (size_t)c * DIN + oct * 8);
            *reinterpret_cast<uint4*>(&Bt[c][oct * 8]) = u;
        }
        __syncthreads();

#pragma unroll
        for (int kc = 0; kc < 4; ++kc) {
            bf16x8 a = *reinterpret_cast<const bf16x8*>(&At[w * 16 + lr][kc * 32 + lk * 8]);
#pragma unroll
            for (int ct = 0; ct < 8; ++ct) {
                bf16x8 b = *reinterpret_cast<const bf16x8*>(&Bt[ct * 16 + lr][kc * 32 + lk * 8]);
                acc[ct] = __builtin_amdgcn_mfma_f32_16x16x32_bf16(a, b, acc[ct], 0, 0, 0);
            }
        }
    }

#pragma unroll
    for (int ct = 0; ct < 8; ++ct) {
        int col = ct * 16 + lr;
        float bv = bias[col];
#pragma unroll
        for (int r = 0; r < 4; ++r) {
            int row = mbase + w * 16 + lk * 4 + r;
            if (row < N_NODES)
                out[(size_t)row * DOUT + col] = fmaxf(acc[ct][r] + bv, 0.f);
        }
    }
}

// ---------------------------------------------------------------------------
// Fallback fused kernel (round-6 structure) + its fill, used if ws too small.
// ---------------------------------------------------------------------------
__global__ __launch_bounds__(256) void k_fill_direct(const int* __restrict__ src0,
                                                     const int* __restrict__ dst0,
                                                     const int* __restrict__ src1,
                                                     const int* __restrict__ dst1,
                                                     const int* __restrict__ src2,
                                                     const int* __restrict__ dst2,
                                                     int* __restrict__ cur,
                                                     unsigned short* __restrict__ slots) {
    int e = blockIdx.x * 256 + threadIdx.x;
    if (e >= E_EDGES) return;
    int d0 = dst0[e];
    int p0 = atomicAdd(&cur[0 * N_NODES + d0], 1);
    if (p0 < SLOT) slots[(size_t)(0 * N_NODES + d0) * SLOT + p0] = (unsigned short)src0[e];
    int d1 = dst1[e];
    int p1 = atomicAdd(&cur[1 * N_NODES + d1], 1);
    if (p1 < SLOT) slots[(size_t)(1 * N_NODES + d1) * SLOT + p1] = (unsigned short)src1[e];
    int d2 = dst2[e];
    int p2 = atomicAdd(&cur[2 * N_NODES + d2], 1);
    if (p2 < SLOT) slots[(size_t)(2 * N_NODES + d2) * SLOT + p2] = (unsigned short)src2[e];
}

__global__ __launch_bounds__(256) void k_fused_fb(const float* __restrict__ x,
                                                  const int* __restrict__ cur,
                                                  const unsigned short* __restrict__ slots,
                                                  const float* __restrict__ W0,
                                                  const float* __restrict__ W1,
                                                  const float* __restrict__ W2,
                                                  const float* __restrict__ Wl,
                                                  const float* __restrict__ bias,
                                                  float* __restrict__ out) {
    __shared__ float Ag[BM][132];
    __shared__ float Bs[KB][DOUT];

    const int tid   = threadIdx.x;
    const int mbase = blockIdx.x * BM;
    const int wave  = tid >> 6;
    const int lane  = tid & 63;
    const int g     = lane >> 4;
    const int li    = lane & 15;
    const int rg    = tid >> 5;
    const int cg    = tid & 31;

    float acc[8][4];
#pragma unroll
    for (int i = 0; i < 8; ++i)
#pragma unroll
        for (int j = 0; j < 4; ++j) acc[i][j] = 0.f;

    for (int rel = 0; rel < 4; ++rel) {
        __syncthreads();
        if (rel < 3) {
#pragma unroll
            for (int t = 0; t < 4; ++t) {
                const int local = wave * 16 + g * 4 + t;
                const int node  = mbase + local;
                float aA0 = 0.f, aA1 = 0.f, aA2 = 0.f, aA3 = 0.f;
                float aB0 = 0.f, aB1 = 0.f, aB2 = 0.f, aB3 = 0.f;
                int dd = 0;
                if (node < N_NODES) {
                    const int seg = rel * N_NODES + node;
                    int dtrue = cur[seg];
                    int d = min(dtrue, SLOT);
                    dd = dtrue;
                    const unsigned short* sb = slots + (size_t)seg * SLOT;
                    const float* xbp = x + (size_t)li * 8;
                    int i = 0;
                    for (; i + 4 <= d; i += 4) {
                        ushort4 s4 = *reinterpret_cast<const ushort4*>(sb + i);
                        const float* q0 = xbp + (size_t)s4.x * DIN;
                        const float* q1 = xbp + (size_t)s4.y * DIN;
                        const float* q2 = xbp + (size_t)s4.z * DIN;
                        const float* q3 = xbp + (size_t)s4.w * DIN;
                        float4 u0 = *reinterpret_cast<const float4*>(q0);
                        float4 w0 = *reinterpret_cast<const float4*>(q0 + 4);
                        float4 u1 = *reinterpret_cast<const float4*>(q1);
                        float4 w1 = *reinterpret_cast<const float4*>(q1 + 4);
                        float4 u2 = *reinterpret_cast<const float4*>(q2);
                        float4 w2 = *reinterpret_cast<const float4*>(q2 + 4);
                        float4 u3 = *reinterpret_cast<const float4*>(q3);
                        float4 w3 = *reinterpret_cast<const float4*>(q3 + 4);
                        aA0 += (u0.x + u1.x) + (u2.x + u3.x);
                        aA1 += (u0.y + u1.y) + (u2.y + u3.y);
                        aA2 += (u0.z + u1.z) + (u2.z + u3.z);
                        aA3 += (u0.w + u1.w) + (u2.w + u3.w);
                        aB0 += (w0.x + w1.x) + (w2.x + w3.x);
                        aB1 += (w0.y + w1.y) + (w2.y + w3.y);
                        aB2 += (w0.z + w1.z) + (w2.z + w3.z);
                        aB3 += (w0.w + w1.w) + (w2.w + w3.w);
                    }
                    for (; i < d; ++i) {
                        int s0 = sb[i];
                        const float* q0 = xbp + (size_t)s0 * DIN;
                        float4 u0 = *reinterpret_cast<const float4*>(q0);
                        float4 w0 = *reinterpret_cast<const float4*>(q0 + 4);
                        aA0 += u0.x; aA1 += u0.y; aA2 += u0.z; aA3 += u0.w;
                        aB0 += w0.x; aB1 += w0.y; aB2 += w0.z; aB3 += w0.w;
                    }
                }
                const float sc = 1.0f / (float)max(dd, 1);
                *reinterpret_cast<float4*>(&Ag[local][li * 8]) =
                    make_float4(aA0 * sc, aA1 * sc, aA2 * sc, aA3 * sc);
                *reinterpret_cast<float4*>(&Ag[local][li * 8 + 4]) =
                    make_float4(aB0 * sc, aB1 * sc, aB2 * sc, aB3 * sc);
            }
        } else {
#pragma unroll
            for (int j = 0; j < 8; ++j) {
                int idx = tid + j * 256;
                int row = idx >> 5;
                int q   = idx & 31;
                int node = mbase + row;
                float4 v = make_float4(0.f, 0.f, 0.f, 0.f);
                if (node < N_NODES)
                    v = *reinterpret_cast<const float4*>(x + (size_t)node * DIN + q * 4);
                *reinterpret_cast<float4*>(&Ag[row][q * 4]) = v;
            }
        }
        __syncthreads();

        const float* W = (rel == 0) ? W0 : (rel == 1) ? W1 : (rel == 2) ? W2 : Wl;
        for (int kc = 0; kc < 16; ++kc) {
            {
                int kk = tid >> 5;
                int cq = tid & 31;
                float4 v = *reinterpret_cast<const float4*>(W + (size_t)(kc * KB + kk) * DOUT + cq * 4);
                *reinterpret_cast<float4*>(&Bs[kk][cq * 4]) = v;
            }
            __syncthreads();
#pragma unroll
            for (int k = 0; k < KB; ++k) {
                float a[8], bb[4];
#pragma unroll
                for (int i = 0; i < 8; ++i) a[i] = Ag[rg * 8 + i][kc * KB + k];
                *reinterpret_cast<float4*>(&bb[0]) = *reinterpret_cast<const float4*>(&Bs[k][cg * 4]);
#pragma unroll
                for (int i = 0; i < 8; ++i)
#pragma unroll
                    for (int j = 0; j < 4; ++j) acc[i][j] += a[i] * bb[j];
            }
            __syncthreads();
        }
    }

    float4 bv = *reinterpret_cast<const float4*>(bias + cg * 4);
#pragma unroll
    for (int i = 0; i < 8; ++i) {
        int node = mbase + rg * 8 + i;
        if (node < N_NODES) {
            float4 o;
            o.x = fmaxf(acc[i][0] + bv.x, 0.f);
            o.y = fmaxf(acc[i][1] + bv.y, 0.f);
            o.z = fmaxf(acc[i][2] + bv.z, 0.f);
            o.w = fmaxf(acc[i][3] + bv.w, 0.f);
            *reinterpret_cast<float4*>(out + (size_t)node * DOUT + cg * 4) = o;
        }
    }
}

// ---------------------------------------------------------------------------
extern "C" void kernel_launch(void* const* d_in, const int* in_sizes, int n_in,
                              void* d_out, int out_size, void* d_ws, size_t ws_size,
                              hipStream_t stream) {
    const float* x    = (const float*)d_in[0];
    const int* src0   = (const int*)d_in[1];
    const int* dst0   = (const int*)d_in[2];
    const int* src1   = (const int*)d_in[3];
    const int* dst1   = (const int*)d_in[4];
    const int* src2   = (const int*)d_in[5];
    const int* dst2   = (const int*)d_in[6];
    const float* W0   = (const float*)d_in[7];
    const float* W1   = (const float*)d_in[8];
    const float* W2   = (const float*)d_in[9];
    const float* Wl   = (const float*)d_in[10];
    const float* bias = (const float*)d_in[11];
    float* out        = (float*)d_out;

    // overlapped layout (only one path runs):
    //   region0: gcnt (9.4KB) / cur (600KB)        -> 600KB
    //   region1: bins (9.6MB) / slots (12MB)       -> 12MB
    //   xb 12.8MB | aggb 38.4MB | Wtb 128KB
    const size_t r0 = ((size_t)NREL * N_NODES * sizeof(int) + 255) & ~(size_t)255;
    const size_t r1 = ((size_t)NREL * N_NODES * SLOT * sizeof(unsigned short) + 255) & ~(size_t)255;
    const size_t sz_xb   = ((size_t)N_NODES * DIN * sizeof(unsigned short) + 255) & ~(size_t)255;
    const size_t sz_aggb = ((size_t)NREL * N_NODES * DIN * sizeof(unsigned short) + 255) & ~(size_t)255;
    const size_t sz_wtb  = ((size_t)4 * DIN * DOUT * sizeof(unsigned short) + 255) & ~(size_t)255;

    char* p = (char*)d_ws;
    int* gcnt             = (int*)p;             // also 'cur' for fallback
    unsigned short* slots = (unsigned short*)(p + r0);
    unsigned int* bins    = (unsigned int*)(p + r0);
    unsigned short* xb    = (unsigned short*)(p + r0 + r1);
    unsigned short* aggb  = (unsigned short*)(p + r0 + r1 + sz_xb);
    unsigned short* Wtb   = (unsigned short*)(p + r0 + r1 + sz_xb + sz_aggb);
    const size_t need = r0 + r1 + sz_xb + sz_aggb + sz_wtb;

    if (ws_size >= need) {
        hipMemsetAsync(gcnt, 0, (size_t)NREL * NB * sizeof(int), stream);
        k_binfill<<<NREL * NCHUNK, 256, 0, stream>>>(src0, dst0, src1, dst1, src2, dst2,
                                                     gcnt, bins);
        k_xcast<<<(N_NODES * DIN / 8 + 255) / 256, 256, 0, stream>>>(x, xb);
        k_wcast<<<(4 * DIN * DOUT + 255) / 256, 256, 0, stream>>>(W0, W1, W2, Wl, Wtb);
        k_gather<<<NREL * NB, 256, 0, stream>>>(xb, gcnt, bins, aggb);
        k_gemm_mfma<<<NB, 256, 0, stream>>>(xb, aggb, Wtb, bias, out);
    } else {
        hipMemsetAsync(gcnt, 0, (size_t)NREL * N_NODES * sizeof(int), stream);
        const int eb = (E_EDGES + 255) / 256;
        k_fill_direct<<<eb, 256, 0, stream>>>(src0, dst0, src1, dst1, src2, dst2, gcnt, slots);
        k_fused_fb<<<NB, 256, 0, stream>>>(x, gcnt, slots, W0, W1, W2, Wl, bias, out);
    }
}